// Round 2
// baseline (249.415 us; speedup 1.0000x reference)
//
#include <hip/hip_runtime.h>
#include <hip/hip_bf16.h>

#define TSTEPS 127
#define HDIM   128
#define NB     16
#define NBATCH 2048

typedef __attribute__((ext_vector_type(8))) short bfrag;
typedef __attribute__((ext_vector_type(4))) float f32x4;

static __device__ __forceinline__ unsigned short f2bf(float f) {
  union { float f; unsigned u; } v; v.f = f;
  unsigned r = (v.u + 0x7FFFu + ((v.u >> 16) & 1u)) >> 16;  // RNE
  return (unsigned short)r;
}
static __device__ __forceinline__ float sigm(float x) {
  return 1.0f / (1.0f + __expf(-x));
}
static __device__ __forceinline__ float tanh_f(float x) {
  return 2.0f / (1.0f + __expf(-2.0f * x)) - 1.0f;  // = tanh(x)
}

// 256 blocks: bid<128 -> LSTM1 (X_tilde + X_encoded[:, :128]); bid>=128 -> LSTM2.
// Each block: 16 batches, all 127 steps. 8 waves; wave w owns u-range [16w,16w+16)
// across all 4 gate types -> i,f,g,o for a (batch,u) pair share a lane+reg index.
// OUTPUT IS FP32 (reference output dtype); comparison is bf16-tolerant, which
// permits bf16 internal compute (weights/h/xt) with fp32 accumulation.
__global__ __launch_bounds__(512, 2)   // 2 waves/EU = 1 block/CU -> 256 VGPR budget, no spills
void enc_kernel(const float* __restrict__ X, const float* __restrict__ yprev,
                const float* __restrict__ Wa,
                const float* __restrict__ Wih1, const float* __restrict__ Whh1,
                const float* __restrict__ bih1, const float* __restrict__ bhh1,
                const float* __restrict__ Wih2, const float* __restrict__ Whh2,
                const float* __restrict__ bih2, const float* __restrict__ bhh2,
                float* __restrict__ out)
{
  const int tid  = threadIdx.x;
  const int wv   = tid >> 6;
  const int lane = tid & 63;
  const int l15  = lane & 15;
  const int lg   = lane >> 4;            // k-group 0..3
  const int lstm  = blockIdx.x >> 7;
  const int btile = blockIdx.x & 127;

  const float* Wih = lstm ? Wih2 : Wih1;
  const float* Whh = lstm ? Whh2 : Whh1;
  const float* bih = lstm ? bih2 : bih1;
  const float* bhh = lstm ? bhh2 : bhh1;
  const int Kin = lstm ? 15 : 16;

  // A-operand staging only; weights live in registers. XOR-swizzle (^(row&7)<<3
  // on element idx) keeps the stride-128 h reads ~conflict-free (T2 pattern).
  __shared__ __align__(16) unsigned short h_lds[2][NB * HDIM];
  __shared__ __align__(16) unsigned short xt_lds[2][NB * 40];  // K=16 data + zero pad to 32 (stride 40: bank-spread)

  // ---- hoist time-invariant weight B-fragments into registers ----
  // wave w, gate-type gt -> N-tile (gt*8 + w); B-frag lane: n=l15, k=lg*8+e.
  bfrag wb[4][4];   // Whh: 4 gate types x 4 K-steps (K=128)
  bfrag wi[4];      // Wih padded to K=32 (zeros past Kin)
  float bias[4];
  #pragma unroll
  for (int gt = 0; gt < 4; ++gt) {
    const int row = (gt * 8 + wv) * 16 + l15;      // global gate index
    const float* wr = Whh + row * HDIM;
    #pragma unroll
    for (int ks = 0; ks < 4; ++ks) {
      const int k0 = ks * 32 + lg * 8;
      bfrag v;
      #pragma unroll
      for (int e = 0; e < 8; ++e) v[e] = (short)f2bf(wr[k0 + e]);
      wb[gt][ks] = v;
    }
    bfrag v;
    #pragma unroll
    for (int e = 0; e < 8; ++e) {
      const int k = lg * 8 + e;
      v[e] = (k < Kin) ? (short)f2bf(Wih[row * Kin + k]) : (short)0;
    }
    wi[gt] = v;
    bias[gt] = bih[row] + bhh[row];
  }

  for (int i = tid; i < 2 * NB * HDIM; i += 512) ((unsigned short*)h_lds)[i] = 0;
  for (int i = tid; i < 2 * NB * 40;   i += 512) ((unsigned short*)xt_lds)[i] = 0;

  // ---- attention weights: h/c terms are k-constant -> cancel in softmax;
  //      feats are time-invariant -> a[b,k] computed ONCE ----
  float a_bk = 0.0f;
  const int bloc = (tid >> 4) & 15;
  const int kf   = tid & 15;
  const size_t bg = (size_t)btile * NB + bloc;
  if (tid < 256) {
    float s = -1e30f;                    // K2=15: kf==15 lane gets weight 0
    if (kf < Kin) {
      s = 0.0f;
      const float* xrow = X + bg * TSTEPS * 15;
      const float* yrow = yprev + bg * TSTEPS;
      for (int t = 0; t < TSTEPS; ++t) {
        const float wa = Wa[256 + t];    // Wa[2H + t]
        float feat;
        if (lstm == 0) feat = (kf < 15) ? xrow[t * 15 + kf] : yrow[t];
        else           feat = xrow[t * 15 + kf] * yrow[t];   // kf<15 guaranteed
        s += feat * wa;
      }
    }
    float mx = s;
    #pragma unroll
    for (int m = 1; m < 16; m <<= 1) mx = fmaxf(mx, __shfl_xor(mx, m));
    const float e = __expf(s - mx);
    float sum = e;
    #pragma unroll
    for (int m = 1; m < 16; m <<= 1) sum += __shfl_xor(sum, m);
    a_bk = e / sum;
  }

  __syncthreads();

  float cr[4] = {0.f, 0.f, 0.f, 0.f};   // c state: batch lg*4+r, u = wv*16+l15
  float xv = 0.f, yv = 0.f;             // input prefetch regs
  if (tid < 256) {
    yv = yprev[bg * TSTEPS];
    if (kf < 15) xv = X[bg * TSTEPS * 15 + kf];
  }
  const size_t XT_TOTAL = (size_t)NBATCH * TSTEPS * 16;
  const int u = wv * 16 + l15;

  for (int t = 0; t < TSTEPS; ++t) {
    const int cur = t & 1;
    // ---- stage xt(t), emit X_tilde (fp32), prefetch t+1 ----
    if (tid < 256) {
      float feat;
      if (lstm == 0) feat = (kf < 15) ? xv : yv;
      else           feat = (kf < 15) ? xv * yv : 0.0f;
      const float xt = a_bk * feat;
      xt_lds[cur][bloc * 40 + kf] = f2bf(xt);
      if (lstm == 0) out[(bg * TSTEPS + t) * 16 + kf] = xt;
      if (t + 1 < TSTEPS) {
        yv = yprev[bg * TSTEPS + t + 1];
        if (kf < 15) xv = X[(bg * TSTEPS + t + 1) * 15 + kf];
      }
    }
    __syncthreads();   // xt(t) ready; h(t-1) writes (pre-barrier, prev iter) visible

    // ---- A-fragments: h from buffer (t-1)&1, xt from buffer t&1 ----
    bfrag ah[4], ax;
    #pragma unroll
    for (int ks = 0; ks < 4; ++ks) {
      const int idx = (l15 * HDIM + ks * 32 + lg * 8) ^ ((l15 & 7) << 3);
      ah[ks] = *(const bfrag*)&h_lds[cur ^ 1][idx];
    }
    ax = *(const bfrag*)&xt_lds[cur][l15 * 40 + lg * 8];

    // ---- 20 MFMAs/wave: 4 tiles x (4 K-steps over h + 1 over xt) ----
    f32x4 acc[4];
    #pragma unroll
    for (int gt = 0; gt < 4; ++gt) {
      f32x4 a = {bias[gt], bias[gt], bias[gt], bias[gt]};
      #pragma unroll
      for (int ks = 0; ks < 4; ++ks)
        a = __builtin_amdgcn_mfma_f32_16x16x32_bf16(ah[ks], wb[gt][ks], a, 0, 0, 0);
      a = __builtin_amdgcn_mfma_f32_16x16x32_bf16(ax, wi[gt], a, 0, 0, 0);
      acc[gt] = a;
    }

    // ---- gate nonlinearity: i,f,g,o co-located per lane; c in regs ----
    #pragma unroll
    for (int r = 0; r < 4; ++r) {
      const float ig = sigm(acc[0][r]);
      const float fg = sigm(acc[1][r]);
      const float gg = tanh_f(acc[2][r]);
      const float og = sigm(acc[3][r]);
      const float c = fg * cr[r] + ig * gg;
      cr[r] = c;
      const float h = og * tanh_f(c);
      const int b = lg * 4 + r;
      h_lds[cur][(b * HDIM + u) ^ ((b & 7) << 3)] = f2bf(h);
      const size_t bgr = (size_t)btile * NB + b;
      out[XT_TOTAL + (bgr * TSTEPS + t) * 256 + (size_t)lstm * 128 + u] = h;  // fp32
    }
    // no second barrier: double-buffered h/xt make write targets disjoint from
    // this step's read buffers; next iteration's barrier orders the swap.
  }
}

extern "C" void kernel_launch(void* const* d_in, const int* in_sizes, int n_in,
                              void* d_out, int out_size, void* d_ws, size_t ws_size,
                              hipStream_t stream) {
  const float* X    = (const float*)d_in[0];
  const float* yp   = (const float*)d_in[1];
  const float* Wa   = (const float*)d_in[2];
  // d_in[3] = ba: shift-invariant under softmax, unused
  const float* Wih1 = (const float*)d_in[4];
  const float* Whh1 = (const float*)d_in[5];
  const float* bih1 = (const float*)d_in[6];
  const float* bhh1 = (const float*)d_in[7];
  const float* Wih2 = (const float*)d_in[8];
  const float* Whh2 = (const float*)d_in[9];
  const float* bih2 = (const float*)d_in[10];
  const float* bhh2 = (const float*)d_in[11];
  float* out = (float*)d_out;

  enc_kernel<<<dim3(256), dim3(512), 0, stream>>>(
      X, yp, Wa, Wih1, Whh1, bih1, bhh1, Wih2, Whh2, bih2, bhh2, out);
}

// Round 3
// 239.470 us; speedup vs baseline: 1.0415x; 1.0415x over previous
//
#include <hip/hip_runtime.h>
#include <hip/hip_bf16.h>

#define TSTEPS 127
#define HDIM   128
#define NB     16
#define NBATCH 2048

typedef __attribute__((ext_vector_type(8))) short bfrag;
typedef __attribute__((ext_vector_type(4))) float f32x4;

static __device__ __forceinline__ unsigned short f2bf(float f) {
  union { float f; unsigned u; } v; v.f = f;
  unsigned r = (v.u + 0x7FFFu + ((v.u >> 16) & 1u)) >> 16;  // RNE
  return (unsigned short)r;
}
static __device__ __forceinline__ float sigm(float x) {
  return 1.0f / (1.0f + __expf(-x));
}
static __device__ __forceinline__ float tanh_f(float x) {
  return 2.0f / (1.0f + __expf(-2.0f * x)) - 1.0f;  // = tanh(x)
}

// 256 blocks: bid<128 -> LSTM1 (X_tilde + X_encoded[:, :128]); bid>=128 -> LSTM2.
// 8 waves; wave w owns u-range [16w,16w+16) across all 4 gate types.
// One RAW barrier per step: s_waitcnt lgkmcnt(0) + s_barrier ONLY — global
// stores (h, X_tilde) and t+2 prefetch loads are never drained in-loop
// (__syncthreads' vmcnt(0) drain was ~4x of step time in round 2).
__global__ __launch_bounds__(512, 2)
void enc_kernel(const float* __restrict__ X, const float* __restrict__ yprev,
                const float* __restrict__ Wa,
                const float* __restrict__ Wih1, const float* __restrict__ Whh1,
                const float* __restrict__ bih1, const float* __restrict__ bhh1,
                const float* __restrict__ Wih2, const float* __restrict__ Whh2,
                const float* __restrict__ bih2, const float* __restrict__ bhh2,
                float* __restrict__ out)
{
  const int tid  = threadIdx.x;
  const int wv   = tid >> 6;
  const int lane = tid & 63;
  const int l15  = lane & 15;
  const int lg   = lane >> 4;            // k-group 0..3
  const int lstm  = blockIdx.x >> 7;
  const int btile = blockIdx.x & 127;

  const float* Wih = lstm ? Wih2 : Wih1;
  const float* Whh = lstm ? Whh2 : Whh1;
  const float* bih = lstm ? bih2 : bih1;
  const float* bhh = lstm ? bhh2 : bhh1;
  const int Kin = lstm ? 15 : 16;

  // Swizzle ^((row&15)<<3) on the element index: reads conflict-free,
  // h u16-writes ~4-way (was 8-way with the &7 mask).
  __shared__ __align__(16) unsigned short h_lds[2][NB * HDIM];
  __shared__ __align__(16) unsigned short xt_lds[2][NB * 40];

  // ---- time-invariant weight B-fragments in registers ----
  bfrag wb[4][4];
  bfrag wi[4];
  float bias[4];
  #pragma unroll
  for (int gt = 0; gt < 4; ++gt) {
    const int row = (gt * 8 + wv) * 16 + l15;
    const float* wr = Whh + row * HDIM;
    #pragma unroll
    for (int ks = 0; ks < 4; ++ks) {
      const int k0 = ks * 32 + lg * 8;
      bfrag v;
      #pragma unroll
      for (int e = 0; e < 8; ++e) v[e] = (short)f2bf(wr[k0 + e]);
      wb[gt][ks] = v;
    }
    bfrag v;
    #pragma unroll
    for (int e = 0; e < 8; ++e) {
      const int k = lg * 8 + e;
      v[e] = (k < Kin) ? (short)f2bf(Wih[row * Kin + k]) : (short)0;
    }
    wi[gt] = v;
    bias[gt] = bih[row] + bhh[row];
  }

  // ---- attention (no LDS): h/c terms cancel in softmax; time-invariant ----
  float a_bk = 0.0f;
  const int bloc = (tid >> 4) & 15;
  const int kf   = tid & 15;
  const size_t bg = (size_t)btile * NB + bloc;
  if (tid < 256) {
    float s = -1e30f;
    if (kf < Kin) {
      s = 0.0f;
      const float* xrow = X + bg * TSTEPS * 15;
      const float* yrow = yprev + bg * TSTEPS;
      for (int t = 0; t < TSTEPS; ++t) {
        const float wa = Wa[256 + t];
        float feat;
        if (lstm == 0) feat = (kf < 15) ? xrow[t * 15 + kf] : yrow[t];
        else           feat = xrow[t * 15 + kf] * yrow[t];
        s += feat * wa;
      }
    }
    float mx = s;
    #pragma unroll
    for (int m = 1; m < 16; m <<= 1) mx = fmaxf(mx, __shfl_xor(mx, m));
    const float e = __expf(s - mx);
    float sum = e;
    #pragma unroll
    for (int m = 1; m < 16; m <<= 1) sum += __shfl_xor(sum, m);
    a_bk = e / sum;
  }

  // ---- zero LDS (incl. xt K-pad), then barrier BEFORE prologue staging ----
  for (int i = tid; i < 2 * NB * HDIM; i += 512) ((unsigned short*)h_lds)[i] = 0;
  for (int i = tid; i < 2 * NB * 40;   i += 512) ((unsigned short*)xt_lds)[i] = 0;
  __syncthreads();

  // ---- strength-reduced output/input pointers ----
  const size_t XT_TOTAL = (size_t)NBATCH * TSTEPS * 16;
  const int u = wv * 16 + l15;
  float* pH[4];
  #pragma unroll
  for (int r = 0; r < 4; ++r) {
    const int b = lg * 4 + r;
    const size_t bgr = (size_t)btile * NB + b;
    pH[r] = out + XT_TOTAL + bgr * (TSTEPS * 256) + (size_t)lstm * 128 + u;
  }
  float* pXT = out + bg * (TSTEPS * 16) + kf;
  const float* pX = X + bg * (TSTEPS * 15) + kf;
  const float* pY = yprev + bg * TSTEPS;

  // ---- prologue: stage xt(0), prefetch (xv,yv) for s=1 ----
  float xv = 0.f, yv = 0.f;
  if (tid < 256) {
    yv = pY[0];
    if (kf < 15) xv = pX[0];
    float feat;
    if (lstm == 0) feat = (kf < 15) ? xv : yv;
    else           feat = (kf < 15) ? xv * yv : 0.0f;
    const float xt = a_bk * feat;
    xt_lds[0][bloc * 40 + kf] = f2bf(xt);
    if (lstm == 0) pXT[0] = xt;
    yv = pY[1];
    if (kf < 15) xv = pX[15];
  }
  __syncthreads();

  float cr[4] = {0.f, 0.f, 0.f, 0.f};

  #pragma unroll 2
  for (int t = 0; t < TSTEPS; ++t) {
    // ---- A-fragments: h(t-1) from buf (t+1)&1, xt(t) from buf t&1 ----
    bfrag ah[4], ax;
    #pragma unroll
    for (int ks = 0; ks < 4; ++ks) {
      const int idx = (l15 * HDIM + ks * 32 + lg * 8) ^ (l15 << 3);
      ah[ks] = *(const bfrag*)&h_lds[(t + 1) & 1][idx];
    }
    ax = *(const bfrag*)&xt_lds[t & 1][l15 * 40 + lg * 8];

    // ---- 20 MFMAs/wave ----
    f32x4 acc[4];
    #pragma unroll
    for (int gt = 0; gt < 4; ++gt) {
      f32x4 a = {bias[gt], bias[gt], bias[gt], bias[gt]};
      #pragma unroll
      for (int ks = 0; ks < 4; ++ks)
        a = __builtin_amdgcn_mfma_f32_16x16x32_bf16(ah[ks], wb[gt][ks], a, 0, 0, 0);
      a = __builtin_amdgcn_mfma_f32_16x16x32_bf16(ax, wi[gt], a, 0, 0, 0);
      acc[gt] = a;
    }

    // ---- gates -> c,h; LDS h(t) into buf t&1; fire-and-forget h stores ----
    #pragma unroll
    for (int r = 0; r < 4; ++r) {
      const float ig = sigm(acc[0][r]);
      const float fg = sigm(acc[1][r]);
      const float gg = tanh_f(acc[2][r]);
      const float og = sigm(acc[3][r]);
      const float c = fg * cr[r] + ig * gg;
      cr[r] = c;
      const float h = og * tanh_f(c);
      const int b = lg * 4 + r;
      h_lds[t & 1][(b * HDIM + u) ^ ((b & 15) << 3)] = f2bf(h);
      *pH[r] = h;          // fp32, never drained in-loop
      pH[r] += 256;
    }

    // ---- stage xt(t+1) into buf (t+1)&1, prefetch s=t+2 ----
    if (tid < 256 && t < TSTEPS - 1) {
      float feat;
      if (lstm == 0) feat = (kf < 15) ? xv : yv;
      else           feat = (kf < 15) ? xv * yv : 0.0f;
      const float xt = a_bk * feat;
      xt_lds[(t + 1) & 1][bloc * 40 + kf] = f2bf(xt);
      if (lstm == 0) pXT[(size_t)(t + 1) * 16] = xt;
      if (t < TSTEPS - 2) {
        yv = pY[t + 2];
        if (kf < 15) xv = pX[(size_t)(t + 2) * 15];
      }
    }

    // ---- RAW barrier: LDS-only ordering; vmcnt free-running ----
    asm volatile("s_waitcnt lgkmcnt(0)" ::: "memory");
    __builtin_amdgcn_s_barrier();
    __builtin_amdgcn_sched_barrier(0);
  }
}

extern "C" void kernel_launch(void* const* d_in, const int* in_sizes, int n_in,
                              void* d_out, int out_size, void* d_ws, size_t ws_size,
                              hipStream_t stream) {
  const float* X    = (const float*)d_in[0];
  const float* yp   = (const float*)d_in[1];
  const float* Wa   = (const float*)d_in[2];
  // d_in[3] = ba: shift-invariant under softmax, unused
  const float* Wih1 = (const float*)d_in[4];
  const float* Whh1 = (const float*)d_in[5];
  const float* bih1 = (const float*)d_in[6];
  const float* bhh1 = (const float*)d_in[7];
  const float* Wih2 = (const float*)d_in[8];
  const float* Whh2 = (const float*)d_in[9];
  const float* bih2 = (const float*)d_in[10];
  const float* bhh2 = (const float*)d_in[11];
  float* out = (float*)d_out;

  enc_kernel<<<dim3(256), dim3(512), 0, stream>>>(
      X, yp, Wa, Wih1, Whh1, bih1, bhh1, Wih2, Whh2, bih2, bhh2, out);
}